// Round 3
// baseline (13235.580 us; speedup 1.0000x reference)
//
#include <hip/hip_runtime.h>
#include <hip/hip_bf16.h>
#include <stdint.h>

typedef __attribute__((ext_vector_type(8))) short short8;
typedef __attribute__((ext_vector_type(4))) float float4v;

__device__ __forceinline__ float bf2f(ushort u) {
  union { float f; uint32_t i; } v; v.i = ((uint32_t)u) << 16; return v.f;
}
__device__ __forceinline__ ushort f2bf(float f) {
  union { float f; uint32_t i; } v; v.f = f;
  uint32_t i = v.i;
  uint32_t r = i + 0x7FFFu + ((i >> 16) & 1u);
  return (ushort)(r >> 16);
}

// ---------------------------------------------------------------------------
// Pack f32 weights (optionally masked) into SPLIT bf16 MFMA B-fragment layout:
// hi at out[idx], lo at out[loOff + idx], where
//   idx = ((kb*NT + nt)*64 + lane)*8 + jj
//   n = nt*16 + (lane&15), k = kb*32 + (lane>>4)*8 + jj
// ---------------------------------------------------------------------------
__global__ __launch_bounds__(256) void pack_w(const float* __restrict__ W,
                                              const float* __restrict__ mask,
                                              ushort* __restrict__ out, int loOff,
                                              int NN, int IT, int NT, int KB) {
  int idx = blockIdx.x * 256 + threadIdx.x;
  int total = KB * NT * 512;
  if (idx >= total) return;
  int jj   = idx & 7;
  int lane = (idx >> 3) & 63;
  int nt   = (idx >> 9) % NT;
  int kb   = (idx >> 9) / NT;
  int n = nt * 16 + (lane & 15);
  int k = kb * 32 + (lane >> 4) * 8 + jj;
  float v = 0.f;
  if (n < NN && k < IT) {
    v = W[(size_t)n * IT + k];
    if (mask) v *= mask[(size_t)n * IT + k];
  }
  ushort hi = f2bf(v);
  float lo = v - bf2f(hi);
  out[idx] = hi;
  out[loOff + idx] = f2bf(lo);
}

// ---------------------------------------------------------------------------
// One CfC cell stage (split-bf16 precision): 32x32 tile of h_new per block.
// A = xc = [seg0 | seg1] (f32 sources), split hi/lo into LDS.
// 4 waves: wave q accumulates matrix q (ff1/ff2/ta/tb):
//   acc = Ah*Bh + Al*Bh + Ah*Bl   (~f32-accurate)
// Epilogue: h = tanh(ff1)*(1-s) + s*tanh(ff2), s = sigmoid(ta+tb+biases).
// ---------------------------------------------------------------------------
template <int IT, int SEG1, int NN, int NT, int KB>
__global__ __launch_bounds__(256)
void cell_stage(const float* __restrict__ a0, int a0_stride,
                const float* __restrict__ a1, int a1_stride,
                const ushort* __restrict__ wq0, const ushort* __restrict__ wq1,
                const ushort* __restrict__ wq2, const ushort* __restrict__ wq3,
                int loOff,
                const float* __restrict__ bias0, const float* __restrict__ bias1,
                const float* __restrict__ bias2, const float* __restrict__ bias3,
                float* __restrict__ hout, float* __restrict__ out2) {
  __shared__ ushort Ah[32][40];   // stride 40: only 2-way bank alias (free)
  __shared__ ushort Al[32][40];
  __shared__ float  Acc[4][32][33];

  const int tid  = threadIdx.x;
  const int wave = tid >> 6;
  const int lane = tid & 63;
  const int quad = lane >> 4;
  const int l16  = lane & 15;
  const int b0   = blockIdx.x * 32;
  const int nt0  = blockIdx.y * 2;
  const int n0   = nt0 * 16;

  const ushort* wf = (wave == 0) ? wq0 : (wave == 1) ? wq1 : (wave == 2) ? wq2 : wq3;

  float4v acc[2][2];
#pragma unroll
  for (int i = 0; i < 2; i++)
#pragma unroll
    for (int j = 0; j < 2; j++) acc[i][j] = float4v{0.f, 0.f, 0.f, 0.f};

  const int sm = tid >> 3;        // staging row 0..31
  const int sk = (tid & 7) * 4;   // staging col base

  for (int kb = 0; kb < KB; kb++) {
    const int k0 = kb * 32;
    __syncthreads();
    {
      const int b = b0 + sm;
#pragma unroll
      for (int e = 0; e < 4; e++) {
        int kg = k0 + sk + e;
        float v = 0.f;
        if (kg < SEG1)      v = a0[(size_t)b * a0_stride + kg];
        else if (kg < IT)   v = a1[(size_t)b * a1_stride + (kg - SEG1)];
        ushort hi = f2bf(v);
        Ah[sm][sk + e] = hi;
        Al[sm][sk + e] = f2bf(v - bf2f(hi));
      }
    }
    __syncthreads();

    short8 bh[2], bl[2];
#pragma unroll
    for (int nt2 = 0; nt2 < 2; nt2++) {
      const size_t fo = ((size_t)(kb * NT + nt0 + nt2) * 64 + lane) * 8;
      bh[nt2] = *(const short8*)(wf + fo);
      bl[nt2] = *(const short8*)(wf + loOff + fo);
    }
#pragma unroll
    for (int mt = 0; mt < 2; mt++) {
      short8 ah = *(const short8*)&Ah[mt * 16 + l16][quad * 8];
      short8 al = *(const short8*)&Al[mt * 16 + l16][quad * 8];
#pragma unroll
      for (int nt2 = 0; nt2 < 2; nt2++) {
        acc[mt][nt2] = __builtin_amdgcn_mfma_f32_16x16x32_bf16(ah, bh[nt2], acc[mt][nt2], 0, 0, 0);
        acc[mt][nt2] = __builtin_amdgcn_mfma_f32_16x16x32_bf16(al, bh[nt2], acc[mt][nt2], 0, 0, 0);
        acc[mt][nt2] = __builtin_amdgcn_mfma_f32_16x16x32_bf16(ah, bl[nt2], acc[mt][nt2], 0, 0, 0);
      }
    }
  }

  // spill accumulators to LDS for cross-wave combine
#pragma unroll
  for (int mt = 0; mt < 2; mt++)
#pragma unroll
    for (int nt2 = 0; nt2 < 2; nt2++)
#pragma unroll
      for (int r = 0; r < 4; r++) {
        int row = mt * 16 + quad * 4 + r;   // batch row in tile
        int col = nt2 * 16 + l16;           // neuron col in tile
        Acc[wave][row][col] = acc[mt][nt2][r];
      }
  __syncthreads();

  {
    const int r  = tid >> 3;
    const int c0 = (tid & 7) * 4;
    const int b  = b0 + r;
#pragma unroll
    for (int e = 0; e < 4; e++) {
      int c = c0 + e;
      int j = n0 + c;
      if (j >= NN) continue;
      float v1 = Acc[0][r][c] + bias0[j];
      float v2 = Acc[1][r][c] + bias1[j];
      float va = Acc[2][r][c] + bias2[j];
      float vb = Acc[3][r][c] + bias3[j];
      float ff1 = tanhf(v1);
      float ff2 = tanhf(v2);
      float z = va + vb;
      float s = 1.f / (1.f + expf(-z));
      float h = ff1 * (1.f - s) + s * ff2;
      hout[(size_t)b * 1024 + j] = h;
      if (out2) out2[(size_t)b * 16384 + j] = h;  // pred[b][t][j], stride T*128
    }
  }
}

// ---------------------------------------------------------------------------
// Final linear, IN PLACE on io (f32, = d_out predictions region):
// io[r][:] <- io[r][:] @ WfcT + bfc. Each block owns 64 rows: load->sync->
// overwrite, no cross-block sharing -> in-place safe. Split-bf16 precision.
// ---------------------------------------------------------------------------
__global__ __launch_bounds__(256)
void final_linear(float* __restrict__ io, const ushort* __restrict__ wfc_frag,
                  int loOff, const float* __restrict__ bfc) {
  __shared__ ushort Ah[64][136];
  __shared__ ushort Al[64][136];
  const int tid = threadIdx.x;
  const int wave = tid >> 6, lane = tid & 63, quad = lane >> 4, l16 = lane & 15;
  const size_t r0 = (size_t)blockIdx.x * 64;
  {
    const int row = tid >> 2;
    const int cb  = (tid & 3) * 32;
    const float* src = io + (r0 + row) * 128 + cb;
#pragma unroll
    for (int e = 0; e < 32; e++) {
      float v = src[e];
      ushort hi = f2bf(v);
      Ah[row][cb + e] = hi;
      Al[row][cb + e] = f2bf(v - bf2f(hi));
    }
  }
  __syncthreads();
  float4v acc[8];
#pragma unroll
  for (int i = 0; i < 8; i++) acc[i] = float4v{0.f, 0.f, 0.f, 0.f};
#pragma unroll
  for (int kb = 0; kb < 4; kb++) {
    short8 ah = *(const short8*)&Ah[wave * 16 + l16][kb * 32 + quad * 8];
    short8 al = *(const short8*)&Al[wave * 16 + l16][kb * 32 + quad * 8];
#pragma unroll
    for (int nt = 0; nt < 8; nt++) {
      const size_t fo = ((size_t)(kb * 8 + nt) * 64 + lane) * 8;
      short8 bh = *(const short8*)(wfc_frag + fo);
      short8 bl = *(const short8*)(wfc_frag + loOff + fo);
      acc[nt] = __builtin_amdgcn_mfma_f32_16x16x32_bf16(ah, bh, acc[nt], 0, 0, 0);
      acc[nt] = __builtin_amdgcn_mfma_f32_16x16x32_bf16(al, bh, acc[nt], 0, 0, 0);
      acc[nt] = __builtin_amdgcn_mfma_f32_16x16x32_bf16(ah, bl, acc[nt], 0, 0, 0);
    }
  }
  __syncthreads();   // all reads of io done before overwrite
#pragma unroll
  for (int nt = 0; nt < 8; nt++) {
    int col = nt * 16 + l16;
    float bb = bfc[col];
#pragma unroll
    for (int r = 0; r < 4; r++) {
      int row = wave * 16 + quad * 4 + r;
      io[(r0 + row) * 128 + col] = acc[nt][r] + bb;
    }
  }
}

// ---------------------------------------------------------------------------
extern "C" void kernel_launch(void* const* d_in, const int* in_sizes, int n_in,
                              void* d_out, int out_size, void* d_ws, size_t ws_size,
                              hipStream_t stream) {
  const int B = 512, T = 128;
  const float* x    = (const float*)d_in[0];
  const float* h0in = (const float*)d_in[1];

  // setup_inputs order: 0=x 1=h0 | per layer l: mask, Wff1, Wff2, Wta, Wtb,
  // bff1, bff2, bta, btb  (l=0: 2..10, l=1: 11..19, l=2: 20..28) | 29=Wfc 30=bfc
  const int maskIdx[3] = {2, 11, 20};
  const int wIdx[3]    = {3, 12, 21};
  const float* Wfc = (const float*)d_in[29];
  const float* bfc = (const float*)d_in[30];

  const int KBs[3] = {33, 28, 16};
  const int NTs[3] = {34, 24, 8};
  const int NNs[3] = {538, 358, 128};
  const int ITs[3] = {1050, 896, 486};

  // workspace: split packed weights (~15.8 MB) + f32 h ping-pong (4 MB)
  ushort* ws = (ushort*)d_ws;
  size_t off = 0;
  ushort* wf[3][4];
  int loOff[3];
  for (int l = 0; l < 3; l++) {
    loOff[l] = KBs[l] * NTs[l] * 512;
    for (int q = 0; q < 4; q++) {
      wf[l][q] = ws + off;
      off += (size_t)2 * loOff[l];
    }
  }
  int wfcLo = 4 * 8 * 512;
  ushort* wfc_f = ws + off; off += (size_t)2 * wfcLo;
  off = (off + 1) & ~(size_t)1;  // align to 4B for float
  float* hb0 = (float*)(ws + off); off += (size_t)B * 1024 * 2;
  float* hb1 = (float*)(ws + off); off += (size_t)B * 1024 * 2;

  float* pred = (float*)d_out;                      // [B*T][128]
  float* hn   = (float*)d_out + (size_t)B * T * 128;

  // pack weights (mask applies to ff1/ff2 only)
  for (int l = 0; l < 3; l++) {
    int total = loOff[l];
    int blocks = (total + 255) / 256;
    for (int q = 0; q < 4; q++) {
      const float* m = (q < 2) ? (const float*)d_in[maskIdx[l]] : nullptr;
      pack_w<<<blocks, 256, 0, stream>>>((const float*)d_in[wIdx[l] + q], m, wf[l][q],
                                         loOff[l], NNs[l], ITs[l], NTs[l], KBs[l]);
    }
  }
  pack_w<<<(wfcLo + 255) / 256, 256, 0, stream>>>(Wfc, nullptr, wfc_f, wfcLo, 128, 128, 8, 4);

  hipMemcpyAsync(hb0, h0in, (size_t)B * 1024 * sizeof(float),
                 hipMemcpyDeviceToDevice, stream);

  for (int t = 0; t < T; t++) {
    const float* hr = (t & 1) ? hb1 : hb0;
    float*       hw = (t & 1) ? hb0 : hb1;
    // layer 0: xc = [x[:,t,:], h0_old]
    cell_stage<1050, 512, 538, 34, 33><<<dim3(16, 17), 256, 0, stream>>>(
        x + (size_t)t * 512, T * 512, hr, 1024,
        wf[0][0], wf[0][1], wf[0][2], wf[0][3], loOff[0],
        (const float*)d_in[7], (const float*)d_in[8],
        (const float*)d_in[9], (const float*)d_in[10],
        hw, nullptr);
    // layer 1: xc = [h0_new, h1_old]
    cell_stage<896, 538, 358, 24, 28><<<dim3(16, 12), 256, 0, stream>>>(
        hw, 1024, hr + 538, 1024,
        wf[1][0], wf[1][1], wf[1][2], wf[1][3], loOff[1],
        (const float*)d_in[16], (const float*)d_in[17],
        (const float*)d_in[18], (const float*)d_in[19],
        hw + 538, nullptr);
    // layer 2: xc = [h1_new, h2_old]; writes h AND pred[:, t, :] (pre-Wfc)
    cell_stage<486, 358, 128, 8, 16><<<dim3(16, 4), 256, 0, stream>>>(
        hw + 538, 1024, hr + 896, 1024,
        wf[2][0], wf[2][1], wf[2][2], wf[2][3], loOff[2],
        (const float*)d_in[25], (const float*)d_in[26],
        (const float*)d_in[27], (const float*)d_in[28],
        hw + 896, pred + (size_t)t * 128);
  }

  // apply Wfc in place on predictions
  final_linear<<<(B * T) / 64, 256, 0, stream>>>(pred, wfc_f, wfcLo, bfc);
  // hn: h written at t=127 (odd -> hb0)
  hipMemcpyAsync(hn, hb0, (size_t)B * 1024 * sizeof(float),
                 hipMemcpyDeviceToDevice, stream);
}